// Round 10
// baseline (183.799 us; speedup 1.0000x reference)
//
#include <hip/hip_runtime.h>
#include <hip/hip_bf16.h>
#include <math.h>

// PinSageConv R10: R6 structure with pipeline depth 2 -> 3 (single-variable).
// Rolled loop, 3-phase body, 3 named reg sets (S0,S1,S2; batch b -> set b%3).
// Phase p: issue(p+3) -> S[p%3], compute(p) from s_stage[p&1], commit(p+1)
// from S[(p+1)%3]. Load->commit lead ~2.5 phases (covers burst/tail latency).
// Everything else identical to the proven 137.7us R6/R9 kernel.

typedef __attribute__((ext_vector_type(8))) short bf16x8;
typedef __attribute__((ext_vector_type(4))) float f32x4;

constexpr float NEG_SLOPE = 0.01f;
constexpr int T_NB  = 16;
constexpr int D_DIM = 256;
constexpr int H_DIM = 256;
constexpr int O_DIM = 256;
constexpr int K2C   = 512;

__device__ __forceinline__ short f2bf(float x) {
    __hip_bfloat16 b = __float2bfloat16(x);
    return *reinterpret_cast<short*>(&b);
}
__device__ __forceinline__ bf16x8 pack2(f32x4 a, f32x4 b) {
    bf16x8 o;
    o[0] = f2bf(a.x); o[1] = f2bf(a.y); o[2] = f2bf(a.z); o[3] = f2bf(a.w);
    o[4] = f2bf(b.x); o[5] = f2bf(b.y); o[6] = f2bf(b.z); o[7] = f2bf(b.w);
    return o;
}

// Qbf plain [256][256]; Wt chunk-transposed: Wt[(o>>4)*64 + (k>>3)][(o&15)*8 + (k&7)]
__global__ void cvt_weights(const float* __restrict__ Qw,
                            const float* __restrict__ Ww,
                            ushort* __restrict__ qdst,
                            ushort* __restrict__ wdst) {
    int i = blockIdx.x * blockDim.x + threadIdx.x;
    if (i < H_DIM * D_DIM) qdst[i] = (ushort)f2bf(Qw[i]);
    if (i < O_DIM * K2C) {
        int o = i >> 9, k = i & 511;
        wdst[((o >> 4) * 64 + (k >> 3)) * 128 + (o & 15) * 8 + (k & 7)] =
            (ushort)f2bf(Ww[i]);
    }
}

// ================= fused kernel =================
constexpr int BLK1 = 512;   // 8 waves
constexpr int NPB1 = 16;    // nodes per block (1 node per pipeline batch)

// swizzled byte offset into s_cat rows of 1024 B
__device__ __forceinline__ unsigned swz(int row, int colbyte) {
    return (unsigned)(row * 1024 + colbyte) ^ ((unsigned)(row & 7) << 4);
}

__global__ __launch_bounds__(BLK1, 4)
void pinsage_fused(const float* __restrict__ h,
                   const int*   __restrict__ nodeset,
                   const int*   __restrict__ nb_nodes,
                   const float* __restrict__ nb_w,
                   const ushort* __restrict__ Qbf,
                   const float* __restrict__ Qb,
                   const ushort* __restrict__ Wt,
                   const float* __restrict__ Wb,
                   float* __restrict__ out,
                   int N)
{
    // bf16 stage: [2 bufs][16 rows][32 slots of 16B], slot = chunk ^ ((row&7)<<2)
    __shared__ ushort s_stage[2 * 16 * 256];    // 16 KB
    __shared__ ushort s_cat[NPB1 * K2C];        // 16 KB, swizzled bf16 [16][512]
    __shared__ int    s_idx[NPB1 * T_NB];
    __shared__ float  s_wt[NPB1 * T_NB];
    __shared__ float  s_winv[NPB1];
    __shared__ int    s_nidx[NPB1];
    __shared__ float  s_part[8][NPB1];
    __shared__ float  s_ninv[NPB1];

    const int tid  = threadIdx.x;
    const int lane = tid & 63;
    const int wid  = tid >> 6;      // 0..7
    const int lrow = lane & 15;
    const int lk   = lane >> 4;
    const int n0   = blockIdx.x * NPB1;

    // staging role: thread covers row = tid>>5 (0..15), 32B chunk ch = tid&31
    const int sRow = tid >> 5;
    const int sCh  = tid & 31;

    // ---- prologue ----
    if (tid < NPB1 * T_NB) {
        int n  = n0 + (tid >> 4);
        int nc = (n < N) ? n : N - 1;
        s_idx[tid] = nb_nodes[nc * T_NB + (tid & 15)];
        s_wt[tid]  = (n < N) ? nb_w[nc * T_NB + (tid & 15)] : 0.f;
    }
    if (tid >= 448 && tid < 448 + NPB1) {
        int r = tid - 448;
        int n = n0 + r;
        s_nidx[r] = nodeset[(n < N) ? n : N - 1];
    }
    __syncthreads();
    if (tid < NPB1) {
        float s = 0.f;
        #pragma unroll
        for (int t = 0; t < T_NB; ++t) s += s_wt[tid * T_NB + t];
        s_winv[tid] = (s == 0.f) ? 1.f : 1.f / s;
    }
    // Q fragments: wave owns col-tiles nt = wid*2 + tt
    bf16x8 bF[2][8];
    float  qb[2];
    #pragma unroll
    for (int tt = 0; tt < 2; ++tt) {
        int nt = wid * 2 + tt;
        const ushort* bb = Qbf + (nt * 16 + lrow) * D_DIM + lk * 8;
        #pragma unroll
        for (int ks = 0; ks < 8; ++ks)
            bF[tt][ks] = *(const bf16x8*)(bb + ks * 32);
        qb[tt] = Qb[nt * 16 + lrow];
    }

    // ---- staging helpers (reg-staged, compiler does counted vmcnt) ----
    auto stage_issue = [&](int b, f32x4& a, f32x4& c) {
        int idx = (b == 16) ? s_nidx[sRow] : s_idx[b * T_NB + sRow];
        const f32x4* src = (const f32x4*)(h + (long)idx * D_DIM + sCh * 8);
        a = src[0]; c = src[1];
    };
    auto stage_commit = [&](int b, f32x4 a, f32x4 c) {
        bf16x8 p = pack2(a, c);
        if (b == 16) {
            *(bf16x8*)((char*)s_cat + swz(sRow, sCh * 16)) = p;
        } else {
            int slot = sCh ^ ((sRow & 7) << 2);
            *(bf16x8*)((char*)s_stage +
                       ((b & 1) * 8192 + sRow * 512 + slot * 16)) = p;
        }
    };

    // ---- per-batch compute: A from s_stage[b&1], epilogue -> s_cat ----
    auto compute = [&](int b) {
        const char* base = (const char*)s_stage + (b & 1) * 8192 + lrow * 512;
        f32x4 acc0 = {0.f, 0.f, 0.f, 0.f}, acc1 = {0.f, 0.f, 0.f, 0.f};
        #pragma unroll
        for (int ks = 0; ks < 8; ++ks) {
            int slot = (ks * 4 + lk) ^ ((lrow & 7) << 2);
            bf16x8 a = *(const bf16x8*)(base + slot * 16);
            acc0 = __builtin_amdgcn_mfma_f32_16x16x32_bf16(a, bF[0][ks], acc0, 0, 0, 0);
            acc1 = __builtin_amdgcn_mfma_f32_16x16x32_bf16(a, bF[1][ks], acc1, 0, 0, 0);
        }
        float w0 = s_wt[b * T_NB + lk * 4 + 0];
        float w1 = s_wt[b * T_NB + lk * 4 + 1];
        float w2 = s_wt[b * T_NB + lk * 4 + 2];
        float w3 = s_wt[b * T_NB + lk * 4 + 3];
        float winv = s_winv[b];
        #pragma unroll
        for (int tt = 0; tt < 2; ++tt) {
            f32x4 acc = tt ? acc1 : acc0;
            float p = 0.f, v;
            v = acc[0] + qb[tt]; v = (v > 0.f) ? v : v * NEG_SLOPE; p += w0 * v;
            v = acc[1] + qb[tt]; v = (v > 0.f) ? v : v * NEG_SLOPE; p += w1 * v;
            v = acc[2] + qb[tt]; v = (v > 0.f) ? v : v * NEG_SLOPE; p += w2 * v;
            v = acc[3] + qb[tt]; v = (v > 0.f) ? v : v * NEG_SLOPE; p += w3 * v;
            p += __shfl_xor(p, 16);
            p += __shfl_xor(p, 32);
            if (lane < 16)
                *(ushort*)((char*)s_cat +
                           swz(b, (D_DIM + (wid * 2 + tt) * 16 + lane) * 2)) =
                    (ushort)f2bf(p * winv);
        }
    };

    // barrier with LDS visibility but NO vmcnt drain
    #define BAR() do { \
        asm volatile("s_waitcnt lgkmcnt(0)" ::: "memory"); \
        __builtin_amdgcn_s_barrier(); \
    } while (0)

    // ---- depth-3 pipeline: named reg sets S0,S1,S2 (batch b -> set b%3) ----
    f32x4 s0a, s0c, s1a, s1c, s2a, s2c;
    stage_issue(0, s0a, s0c);
    stage_issue(1, s1a, s1c);
    stage_issue(2, s2a, s2c);
    stage_commit(0, s0a, s0c);          // waits S0 only; S1,S2 stay in flight
    BAR();

    // phase p: issue(p+3)->S[p%3], compute(p), commit(p+1) from S[(p+1)%3]
    for (int q = 0; q < 5; ++q) {       // phases p = 3q, 3q+1, 3q+2  (0..14)
        const int p = q * 3;
        if (p + 3 <= 16) stage_issue(p + 3, s0a, s0c);
        compute(p);
        stage_commit(p + 1, s1a, s1c);
        BAR();
        if (p + 4 <= 16) stage_issue(p + 4, s1a, s1c);
        compute(p + 1);
        stage_commit(p + 2, s2a, s2c);
        BAR();
        if (p + 5 <= 16) stage_issue(p + 5, s2a, s2c);
        compute(p + 2);
        stage_commit(p + 3, s0a, s0c);
        BAR();
    }
    // phase 15: compute(15); commit(16) = nodeset rows -> s_cat left half (S1)
    compute(15);
    stage_commit(16, s1a, s1c);
    BAR();
    #undef BAR

    // ---- stage B: (16 x 512) @ W^T; wave owns 2 output col-tiles ----
    bf16x8 a2[16];
    #pragma unroll
    for (int ks = 0; ks < 16; ++ks)
        a2[ks] = *(const bf16x8*)((char*)s_cat + swz(lrow, ks * 64 + lk * 16));

    float vout[2][4];
    float sq[4] = {0.f, 0.f, 0.f, 0.f};
    #pragma unroll
    for (int tt = 0; tt < 2; ++tt) {
        int ot_g = wid * 2 + tt;
        int ocol = ot_g * 16 + lrow;
        f32x4 acc = {0.f, 0.f, 0.f, 0.f};
        #pragma unroll
        for (int ks = 0; ks < 16; ++ks) {
            bf16x8 wF = *(const bf16x8*)(Wt + ((ot_g * 64 + ks * 4 + lk) * 128 + lrow * 8));
            acc = __builtin_amdgcn_mfma_f32_16x16x32_bf16(a2[ks], wF, acc, 0, 0, 0);
        }
        float wb = Wb[ocol];
        #pragma unroll
        for (int r = 0; r < 4; ++r) {
            float v = acc[r] + wb;
            v = (v > 0.f) ? v : v * NEG_SLOPE;
            vout[tt][r] = v;
            sq[r] += v * v;
        }
    }
    #pragma unroll
    for (int r = 0; r < 4; ++r) {
        sq[r] += __shfl_xor(sq[r], 1);
        sq[r] += __shfl_xor(sq[r], 2);
        sq[r] += __shfl_xor(sq[r], 4);
        sq[r] += __shfl_xor(sq[r], 8);
    }
    if (lrow == 0) {
        #pragma unroll
        for (int r = 0; r < 4; ++r) s_part[wid][lk * 4 + r] = sq[r];
    }
    __syncthreads();
    if (tid < NPB1) {
        float s = 0.f;
        #pragma unroll
        for (int w = 0; w < 8; ++w) s += s_part[w][tid];
        s_ninv[tid] = (s == 0.f) ? 1.f : 1.f / sqrtf(s);
    }
    __syncthreads();

    #pragma unroll
    for (int r = 0; r < 4; ++r) {
        int node = lk * 4 + r;
        int n = n0 + node;
        if (n < N) {
            float inv = s_ninv[node];
            #pragma unroll
            for (int tt = 0; tt < 2; ++tt)
                out[(long)n * O_DIM + (wid * 2 + tt) * 16 + lrow] = vout[tt][r] * inv;
        }
    }
}

// ================= Fallback (no workspace): monolithic f32-weight =================
__global__ __launch_bounds__(256, 2)
void pinsage_mono(const float* __restrict__ h,
                  const int*   __restrict__ nodeset,
                  const int*   __restrict__ nb_nodes,
                  const float* __restrict__ nb_w,
                  const float* __restrict__ Qw,
                  const float* __restrict__ Qb,
                  const float* __restrict__ Ww,
                  const float* __restrict__ Wb,
                  float* __restrict__ out, int N)
{
    __shared__ ushort s_cat[16 * K2C];
    __shared__ float  s_part[4][16];
    __shared__ float  s_ninv[16];

    const int tid  = threadIdx.x;
    const int lane = tid & 63;
    const int wid  = tid >> 6;
    const int lrow = lane & 15;
    const int lk   = lane >> 4;
    const int n0   = blockIdx.x * 16;

    {
        int r = tid >> 4, j = tid & 15;
        int n = n0 + r;
        int idx = (n < N) ? nodeset[n] : 0;
        const float* src = h + (long)idx * D_DIM + j * 16;
        f32x4 v0 = *(const f32x4*)(src + 0);
        f32x4 v1 = *(const f32x4*)(src + 4);
        f32x4 v2 = *(const f32x4*)(src + 8);
        f32x4 v3 = *(const f32x4*)(src + 12);
        *(bf16x8*)((char*)s_cat + swz(r, j * 32))      = pack2(v0, v1);
        *(bf16x8*)((char*)s_cat + swz(r, j * 32 + 16)) = pack2(v2, v3);
    }

    int   aidx[4];
    float wn[4][4];
    #pragma unroll
    for (int g = 0; g < 4; ++g) {
        int n  = n0 + wid * 4 + g;
        int nc = (n < N) ? n : 0;
        aidx[g] = nb_nodes[nc * T_NB + lrow];
        f32x4 w4 = *(const f32x4*)(nb_w + nc * T_NB + lk * 4);
        float wsum = w4.x + w4.y + w4.z + w4.w;
        wsum += __shfl_xor(wsum, 16);
        wsum += __shfl_xor(wsum, 32);
        float inv = (wsum == 0.f) ? 1.f : 1.f / wsum;
        if (n >= N) inv = 0.f;
        wn[g][0] = w4.x * inv; wn[g][1] = w4.y * inv;
        wn[g][2] = w4.z * inv; wn[g][3] = w4.w * inv;
    }

    bf16x8 aF[4][8];
    #pragma unroll
    for (int g = 0; g < 4; ++g) {
        const float* base = h + (long)aidx[g] * D_DIM + lk * 8;
        #pragma unroll
        for (int ks = 0; ks < 8; ++ks) {
            f32x4 t0 = *(const f32x4*)(base + ks * 32 + 0);
            f32x4 t1 = *(const f32x4*)(base + ks * 32 + 4);
            aF[g][ks] = pack2(t0, t1);
        }
    }

    for (int nt = 0; nt < 16; ++nt) {
        bf16x8 bF[8];
        const float* bb = Qw + (nt * 16 + lrow) * D_DIM + lk * 8;
        #pragma unroll
        for (int ks = 0; ks < 8; ++ks) {
            f32x4 t0 = *(const f32x4*)(bb + ks * 32 + 0);
            f32x4 t1 = *(const f32x4*)(bb + ks * 32 + 4);
            bF[ks] = pack2(t0, t1);
        }
        f32x4 acc[4];
        #pragma unroll
        for (int g = 0; g < 4; ++g) acc[g] = (f32x4){0.f, 0.f, 0.f, 0.f};
        #pragma unroll
        for (int g = 0; g < 4; ++g)
            #pragma unroll
            for (int ks = 0; ks < 8; ++ks)
                acc[g] = __builtin_amdgcn_mfma_f32_16x16x32_bf16(aF[g][ks], bF[ks], acc[g], 0, 0, 0);

        float qb = Qb[nt * 16 + lrow];
        #pragma unroll
        for (int g = 0; g < 4; ++g) {
            float p = 0.f;
            #pragma unroll
            for (int r = 0; r < 4; ++r) {
                float v = acc[g][r] + qb;
                v = (v > 0.f) ? v : v * NEG_SLOPE;
                p += wn[g][r] * v;
            }
            p += __shfl_xor(p, 16);
            p += __shfl_xor(p, 32);
            if (lane < 16) {
                int node = wid * 4 + g;
                *(ushort*)((char*)s_cat + swz(node, (D_DIM + nt * 16 + lane) * 2)) =
                    (ushort)f2bf(p);
            }
        }
    }
    __syncthreads();

    bf16x8 a2[16];
    #pragma unroll
    for (int ks = 0; ks < 16; ++ks)
        a2[ks] = *(const bf16x8*)((char*)s_cat + swz(lrow, ks * 64 + lk * 16));

    float vout[4][4];
    float sq[4] = {0.f, 0.f, 0.f, 0.f};
    #pragma unroll
    for (int ot = 0; ot < 4; ++ot) {
        int ocol = wid * 64 + ot * 16 + lrow;
        f32x4 acc = {0.f, 0.f, 0.f, 0.f};
        const float* bb = Ww + ocol * K2C + lk * 8;
        #pragma unroll
        for (int ks = 0; ks < 16; ++ks) {
            f32x4 t0 = *(const f32x4*)(bb + ks * 32 + 0);
            f32x4 t1 = *(const f32x4*)(bb + ks * 32 + 4);
            bf16x8 bFk = pack2(t0, t1);
            acc = __builtin_amdgcn_mfma_f32_16x16x32_bf16(a2[ks], bFk, acc, 0, 0, 0);
        }
        float wb = Wb[ocol];
        #pragma unroll
        for (int r = 0; r < 4; ++r) {
            float v = acc[r] + wb;
            v = (v > 0.f) ? v : v * NEG_SLOPE;
            vout[ot][r] = v;
            sq[r] += v * v;
        }
    }
    #pragma unroll
    for (int r = 0; r < 4; ++r) {
        sq[r] += __shfl_xor(sq[r], 1);
        sq[r] += __shfl_xor(sq[r], 2);
        sq[r] += __shfl_xor(sq[r], 4);
        sq[r] += __shfl_xor(sq[r], 8);
    }
    if (lrow == 0) {
        #pragma unroll
        for (int r = 0; r < 4; ++r) s_part[wid][lk * 4 + r] = sq[r];
    }
    __syncthreads();
    if (tid < 16) {
        float s = s_part[0][tid] + s_part[1][tid] + s_part[2][tid] + s_part[3][tid];
        s_ninv[tid] = (s == 0.f) ? 1.f : 1.f / sqrtf(s);
    }
    __syncthreads();

    #pragma unroll
    for (int r = 0; r < 4; ++r) {
        int node = lk * 4 + r;
        int n = n0 + node;
        if (n < N) {
            float inv = s_ninv[node];
            #pragma unroll
            for (int ot = 0; ot < 4; ++ot)
                out[(long)n * O_DIM + wid * 64 + ot * 16 + lrow] = vout[ot][r] * inv;
        }
    }
}

extern "C" void kernel_launch(void* const* d_in, const int* in_sizes, int n_in,
                              void* d_out, int out_size, void* d_ws, size_t ws_size,
                              hipStream_t stream)
{
    const float* h        = (const float*)d_in[0];
    const int*   nodeset  = (const int*)  d_in[1];
    const int*   nb_nodes = (const int*)  d_in[2];
    const float* nb_w     = (const float*)d_in[3];
    const float* Qw       = (const float*)d_in[4];
    const float* Qb       = (const float*)d_in[5];
    const float* Ww       = (const float*)d_in[6];
    const float* Wb       = (const float*)d_in[7];
    float*       out      = (float*)d_out;

    int N = in_sizes[1];

    constexpr size_t QBYTES = (size_t)H_DIM * D_DIM * sizeof(ushort);   // 128 KB
    constexpr size_t WBYTES = (size_t)O_DIM * K2C * sizeof(ushort);     // 256 KB

    if (d_ws && ws_size >= QBYTES + WBYTES) {
        ushort* Qbf = (ushort*)d_ws;
        ushort* Wt  = (ushort*)((char*)d_ws + QBYTES);
        cvt_weights<<<(O_DIM * K2C + 255) / 256, 256, 0, stream>>>(Qw, Ww, Qbf, Wt);
        pinsage_fused<<<(N + NPB1 - 1) / NPB1, BLK1, 0, stream>>>(
            h, nodeset, nb_nodes, nb_w, Qbf, Qb, Wt, Wb, out, N);
    } else {
        pinsage_mono<<<(N + 15) / 16, 256, 0, stream>>>(
            h, nodeset, nb_nodes, nb_w, Qw, Qb, Ww, Wb, out, N);
    }
}

// Round 11
// 137.550 us; speedup vs baseline: 1.3362x; 1.3362x over previous
//
#include <hip/hip_runtime.h>
#include <hip/hip_bf16.h>
#include <math.h>

// PinSageConv R11 = R6/R9 revert (proven 137.7 us) -- FINAL STATE.
// Fused, reg-staged depth-2 pipeline. Per block 16 nodes. Each batch (1 node,
// 16 rows x 1KB): threads load 32B f32 to VGPRs (counted vmcnt handled by
// compiler), cvt->bf16, ds_write swizzled. 2-deep double buffer,
// lgkmcnt(0)+raw s_barrier (NO vmcnt drain in loop). Stage-A MFMA with Q
// register-resident (8 waves x 2 col-tiles); agg -> s_cat bf16; nodeset rows
// ride as batch 16 -> s_cat left half. Stage B from s_cat.
// R7 (unrolled depth-3), R8 (2 nodes/phase), R10 (rolled depth-3) all
// regressed (spills / bank conflicts / live-range blowup): the 2-set
// ping-pong is the codegen sweet spot. Random-gather runs ~3 TB/s HBM-side,
// the practical ceiling for 1KB-row random access at this occupancy.

typedef __attribute__((ext_vector_type(8))) short bf16x8;
typedef __attribute__((ext_vector_type(4))) float f32x4;

constexpr float NEG_SLOPE = 0.01f;
constexpr int T_NB  = 16;
constexpr int D_DIM = 256;
constexpr int H_DIM = 256;
constexpr int O_DIM = 256;
constexpr int K2C   = 512;

__device__ __forceinline__ short f2bf(float x) {
    __hip_bfloat16 b = __float2bfloat16(x);
    return *reinterpret_cast<short*>(&b);
}
__device__ __forceinline__ bf16x8 pack2(f32x4 a, f32x4 b) {
    bf16x8 o;
    o[0] = f2bf(a.x); o[1] = f2bf(a.y); o[2] = f2bf(a.z); o[3] = f2bf(a.w);
    o[4] = f2bf(b.x); o[5] = f2bf(b.y); o[6] = f2bf(b.z); o[7] = f2bf(b.w);
    return o;
}

// Qbf plain [256][256]; Wt chunk-transposed: Wt[(o>>4)*64 + (k>>3)][(o&15)*8 + (k&7)]
__global__ void cvt_weights(const float* __restrict__ Qw,
                            const float* __restrict__ Ww,
                            ushort* __restrict__ qdst,
                            ushort* __restrict__ wdst) {
    int i = blockIdx.x * blockDim.x + threadIdx.x;
    if (i < H_DIM * D_DIM) qdst[i] = (ushort)f2bf(Qw[i]);
    if (i < O_DIM * K2C) {
        int o = i >> 9, k = i & 511;
        wdst[((o >> 4) * 64 + (k >> 3)) * 128 + (o & 15) * 8 + (k & 7)] =
            (ushort)f2bf(Ww[i]);
    }
}

// ================= fused kernel =================
constexpr int BLK1 = 512;   // 8 waves
constexpr int NPB1 = 16;    // nodes per block (1 node per pipeline batch)

// swizzled byte offset into s_cat rows of 1024 B
__device__ __forceinline__ unsigned swz(int row, int colbyte) {
    return (unsigned)(row * 1024 + colbyte) ^ ((unsigned)(row & 7) << 4);
}

__global__ __launch_bounds__(BLK1, 4)
void pinsage_fused(const float* __restrict__ h,
                   const int*   __restrict__ nodeset,
                   const int*   __restrict__ nb_nodes,
                   const float* __restrict__ nb_w,
                   const ushort* __restrict__ Qbf,
                   const float* __restrict__ Qb,
                   const ushort* __restrict__ Wt,
                   const float* __restrict__ Wb,
                   float* __restrict__ out,
                   int N)
{
    // bf16 stage: [2 bufs][16 rows][32 slots of 16B], slot = chunk ^ ((row&7)<<2)
    __shared__ ushort s_stage[2 * 16 * 256];    // 16 KB
    __shared__ ushort s_cat[NPB1 * K2C];        // 16 KB, swizzled bf16 [16][512]
    __shared__ int    s_idx[NPB1 * T_NB];
    __shared__ float  s_wt[NPB1 * T_NB];
    __shared__ float  s_winv[NPB1];
    __shared__ int    s_nidx[NPB1];
    __shared__ float  s_part[8][NPB1];
    __shared__ float  s_ninv[NPB1];

    const int tid  = threadIdx.x;
    const int lane = tid & 63;
    const int wid  = tid >> 6;      // 0..7
    const int lrow = lane & 15;
    const int lk   = lane >> 4;
    const int n0   = blockIdx.x * NPB1;

    // staging role: thread covers row = tid>>5 (0..15), 32B chunk ch = tid&31
    const int sRow = tid >> 5;
    const int sCh  = tid & 31;

    // ---- prologue ----
    if (tid < NPB1 * T_NB) {
        int n  = n0 + (tid >> 4);
        int nc = (n < N) ? n : N - 1;
        s_idx[tid] = nb_nodes[nc * T_NB + (tid & 15)];
        s_wt[tid]  = (n < N) ? nb_w[nc * T_NB + (tid & 15)] : 0.f;
    }
    if (tid >= 448 && tid < 448 + NPB1) {
        int r = tid - 448;
        int n = n0 + r;
        s_nidx[r] = nodeset[(n < N) ? n : N - 1];
    }
    __syncthreads();
    if (tid < NPB1) {
        float s = 0.f;
        #pragma unroll
        for (int t = 0; t < T_NB; ++t) s += s_wt[tid * T_NB + t];
        s_winv[tid] = (s == 0.f) ? 1.f : 1.f / s;
    }
    // Q fragments: wave owns col-tiles nt = wid*2 + tt
    bf16x8 bF[2][8];
    float  qb[2];
    #pragma unroll
    for (int tt = 0; tt < 2; ++tt) {
        int nt = wid * 2 + tt;
        const ushort* bb = Qbf + (nt * 16 + lrow) * D_DIM + lk * 8;
        #pragma unroll
        for (int ks = 0; ks < 8; ++ks)
            bF[tt][ks] = *(const bf16x8*)(bb + ks * 32);
        qb[tt] = Qb[nt * 16 + lrow];
    }

    // ---- staging helpers (reg-staged, compiler does counted vmcnt) ----
    auto stage_issue = [&](int b, f32x4& a, f32x4& c) {
        int idx = (b == 16) ? s_nidx[sRow] : s_idx[b * T_NB + sRow];
        const f32x4* src = (const f32x4*)(h + (long)idx * D_DIM + sCh * 8);
        a = src[0]; c = src[1];
    };
    auto stage_commit = [&](int b, f32x4 a, f32x4 c) {
        bf16x8 p = pack2(a, c);
        if (b == 16) {
            *(bf16x8*)((char*)s_cat + swz(sRow, sCh * 16)) = p;
        } else {
            int slot = sCh ^ ((sRow & 7) << 2);
            *(bf16x8*)((char*)s_stage +
                       ((b & 1) * 8192 + sRow * 512 + slot * 16)) = p;
        }
    };

    // ---- per-batch compute: A from s_stage[b&1], epilogue -> s_cat ----
    auto compute = [&](int b) {
        const char* base = (const char*)s_stage + (b & 1) * 8192 + lrow * 512;
        f32x4 acc0 = {0.f, 0.f, 0.f, 0.f}, acc1 = {0.f, 0.f, 0.f, 0.f};
        #pragma unroll
        for (int ks = 0; ks < 8; ++ks) {
            int slot = (ks * 4 + lk) ^ ((lrow & 7) << 2);
            bf16x8 a = *(const bf16x8*)(base + slot * 16);
            acc0 = __builtin_amdgcn_mfma_f32_16x16x32_bf16(a, bF[0][ks], acc0, 0, 0, 0);
            acc1 = __builtin_amdgcn_mfma_f32_16x16x32_bf16(a, bF[1][ks], acc1, 0, 0, 0);
        }
        float w0 = s_wt[b * T_NB + lk * 4 + 0];
        float w1 = s_wt[b * T_NB + lk * 4 + 1];
        float w2 = s_wt[b * T_NB + lk * 4 + 2];
        float w3 = s_wt[b * T_NB + lk * 4 + 3];
        float winv = s_winv[b];
        #pragma unroll
        for (int tt = 0; tt < 2; ++tt) {
            f32x4 acc = tt ? acc1 : acc0;
            float p = 0.f, v;
            v = acc[0] + qb[tt]; v = (v > 0.f) ? v : v * NEG_SLOPE; p += w0 * v;
            v = acc[1] + qb[tt]; v = (v > 0.f) ? v : v * NEG_SLOPE; p += w1 * v;
            v = acc[2] + qb[tt]; v = (v > 0.f) ? v : v * NEG_SLOPE; p += w2 * v;
            v = acc[3] + qb[tt]; v = (v > 0.f) ? v : v * NEG_SLOPE; p += w3 * v;
            p += __shfl_xor(p, 16);
            p += __shfl_xor(p, 32);
            if (lane < 16)
                *(ushort*)((char*)s_cat +
                           swz(b, (D_DIM + (wid * 2 + tt) * 16 + lane) * 2)) =
                    (ushort)f2bf(p * winv);
        }
    };

    // barrier with LDS visibility but NO vmcnt drain
    #define BAR() do { \
        asm volatile("s_waitcnt lgkmcnt(0)" ::: "memory"); \
        __builtin_amdgcn_s_barrier(); \
    } while (0)

    // ---- pipeline: 2-deep, named reg sets (static indexing) ----
    f32x4 uA0, uA1, uB0, uB1;
    stage_issue(0, uA0, uA1);
    stage_issue(1, uB0, uB1);
    stage_commit(0, uA0, uA1);          // waits uA only (uB stays in flight)
    BAR();

    for (int bb = 0; bb < 8; ++bb) {
        const int b = bb * 2;
        // even phase: issue b+2 early, compute b (buf0), commit b+1 (buf1) late
        stage_issue(b + 2, uA0, uA1);
        compute(b);
        stage_commit(b + 1, uB0, uB1);
        BAR();
        // odd phase: issue b+3, compute b+1 (buf1), commit b+2 late
        if (b + 3 <= 16) stage_issue(b + 3, uB0, uB1);
        compute(b + 1);
        stage_commit(b + 2, uA0, uA1);  // b==14 -> commit(16) writes s_cat
        BAR();
    }
    #undef BAR

    // ---- stage B: (16 x 512) @ W^T; wave owns 2 output col-tiles ----
    bf16x8 a2[16];
    #pragma unroll
    for (int ks = 0; ks < 16; ++ks)
        a2[ks] = *(const bf16x8*)((char*)s_cat + swz(lrow, ks * 64 + lk * 16));

    float vout[2][4];
    float sq[4] = {0.f, 0.f, 0.f, 0.f};
    #pragma unroll
    for (int tt = 0; tt < 2; ++tt) {
        int ot_g = wid * 2 + tt;
        int ocol = ot_g * 16 + lrow;
        f32x4 acc = {0.f, 0.f, 0.f, 0.f};
        #pragma unroll
        for (int ks = 0; ks < 16; ++ks) {
            bf16x8 wF = *(const bf16x8*)(Wt + ((ot_g * 64 + ks * 4 + lk) * 128 + lrow * 8));
            acc = __builtin_amdgcn_mfma_f32_16x16x32_bf16(a2[ks], wF, acc, 0, 0, 0);
        }
        float wb = Wb[ocol];
        #pragma unroll
        for (int r = 0; r < 4; ++r) {
            float v = acc[r] + wb;
            v = (v > 0.f) ? v : v * NEG_SLOPE;
            vout[tt][r] = v;
            sq[r] += v * v;
        }
    }
    #pragma unroll
    for (int r = 0; r < 4; ++r) {
        sq[r] += __shfl_xor(sq[r], 1);
        sq[r] += __shfl_xor(sq[r], 2);
        sq[r] += __shfl_xor(sq[r], 4);
        sq[r] += __shfl_xor(sq[r], 8);
    }
    if (lrow == 0) {
        #pragma unroll
        for (int r = 0; r < 4; ++r) s_part[wid][lk * 4 + r] = sq[r];
    }
    __syncthreads();
    if (tid < NPB1) {
        float s = 0.f;
        #pragma unroll
        for (int w = 0; w < 8; ++w) s += s_part[w][tid];
        s_ninv[tid] = (s == 0.f) ? 1.f : 1.f / sqrtf(s);
    }
    __syncthreads();

    #pragma unroll
    for (int r = 0; r < 4; ++r) {
        int node = lk * 4 + r;
        int n = n0 + node;
        if (n < N) {
            float inv = s_ninv[node];
            #pragma unroll
            for (int tt = 0; tt < 2; ++tt)
                out[(long)n * O_DIM + (wid * 2 + tt) * 16 + lrow] = vout[tt][r] * inv;
        }
    }
}

// ================= Fallback (no workspace): monolithic f32-weight =================
__global__ __launch_bounds__(256, 2)
void pinsage_mono(const float* __restrict__ h,
                  const int*   __restrict__ nodeset,
                  const int*   __restrict__ nb_nodes,
                  const float* __restrict__ nb_w,
                  const float* __restrict__ Qw,
                  const float* __restrict__ Qb,
                  const float* __restrict__ Ww,
                  const float* __restrict__ Wb,
                  float* __restrict__ out, int N)
{
    __shared__ ushort s_cat[16 * K2C];
    __shared__ float  s_part[4][16];
    __shared__ float  s_ninv[16];

    const int tid  = threadIdx.x;
    const int lane = tid & 63;
    const int wid  = tid >> 6;
    const int lrow = lane & 15;
    const int lk   = lane >> 4;
    const int n0   = blockIdx.x * 16;

    {
        int r = tid >> 4, j = tid & 15;
        int n = n0 + r;
        int idx = (n < N) ? nodeset[n] : 0;
        const float* src = h + (long)idx * D_DIM + j * 16;
        f32x4 v0 = *(const f32x4*)(src + 0);
        f32x4 v1 = *(const f32x4*)(src + 4);
        f32x4 v2 = *(const f32x4*)(src + 8);
        f32x4 v3 = *(const f32x4*)(src + 12);
        *(bf16x8*)((char*)s_cat + swz(r, j * 32))      = pack2(v0, v1);
        *(bf16x8*)((char*)s_cat + swz(r, j * 32 + 16)) = pack2(v2, v3);
    }

    int   aidx[4];
    float wn[4][4];
    #pragma unroll
    for (int g = 0; g < 4; ++g) {
        int n  = n0 + wid * 4 + g;
        int nc = (n < N) ? n : 0;
        aidx[g] = nb_nodes[nc * T_NB + lrow];
        f32x4 w4 = *(const f32x4*)(nb_w + nc * T_NB + lk * 4);
        float wsum = w4.x + w4.y + w4.z + w4.w;
        wsum += __shfl_xor(wsum, 16);
        wsum += __shfl_xor(wsum, 32);
        float inv = (wsum == 0.f) ? 1.f : 1.f / wsum;
        if (n >= N) inv = 0.f;
        wn[g][0] = w4.x * inv; wn[g][1] = w4.y * inv;
        wn[g][2] = w4.z * inv; wn[g][3] = w4.w * inv;
    }

    bf16x8 aF[4][8];
    #pragma unroll
    for (int g = 0; g < 4; ++g) {
        const float* base = h + (long)aidx[g] * D_DIM + lk * 8;
        #pragma unroll
        for (int ks = 0; ks < 8; ++ks) {
            f32x4 t0 = *(const f32x4*)(base + ks * 32 + 0);
            f32x4 t1 = *(const f32x4*)(base + ks * 32 + 4);
            aF[g][ks] = pack2(t0, t1);
        }
    }

    for (int nt = 0; nt < 16; ++nt) {
        bf16x8 bF[8];
        const float* bb = Qw + (nt * 16 + lrow) * D_DIM + lk * 8;
        #pragma unroll
        for (int ks = 0; ks < 8; ++ks) {
            f32x4 t0 = *(const f32x4*)(bb + ks * 32 + 0);
            f32x4 t1 = *(const f32x4*)(bb + ks * 32 + 4);
            bF[ks] = pack2(t0, t1);
        }
        f32x4 acc[4];
        #pragma unroll
        for (int g = 0; g < 4; ++g) acc[g] = (f32x4){0.f, 0.f, 0.f, 0.f};
        #pragma unroll
        for (int g = 0; g < 4; ++g)
            #pragma unroll
            for (int ks = 0; ks < 8; ++ks)
                acc[g] = __builtin_amdgcn_mfma_f32_16x16x32_bf16(aF[g][ks], bF[ks], acc[g], 0, 0, 0);

        float qb = Qb[nt * 16 + lrow];
        #pragma unroll
        for (int g = 0; g < 4; ++g) {
            float p = 0.f;
            #pragma unroll
            for (int r = 0; r < 4; ++r) {
                float v = acc[g][r] + qb;
                v = (v > 0.f) ? v : v * NEG_SLOPE;
                p += wn[g][r] * v;
            }
            p += __shfl_xor(p, 16);
            p += __shfl_xor(p, 32);
            if (lane < 16) {
                int node = wid * 4 + g;
                *(ushort*)((char*)s_cat + swz(node, (D_DIM + nt * 16 + lane) * 2)) =
                    (ushort)f2bf(p);
            }
        }
    }
    __syncthreads();

    bf16x8 a2[16];
    #pragma unroll
    for (int ks = 0; ks < 16; ++ks)
        a2[ks] = *(const bf16x8*)((char*)s_cat + swz(lrow, ks * 64 + lk * 16));

    float vout[4][4];
    float sq[4] = {0.f, 0.f, 0.f, 0.f};
    #pragma unroll
    for (int ot = 0; ot < 4; ++ot) {
        int ocol = wid * 64 + ot * 16 + lrow;
        f32x4 acc = {0.f, 0.f, 0.f, 0.f};
        const float* bb = Ww + ocol * K2C + lk * 8;
        #pragma unroll
        for (int ks = 0; ks < 16; ++ks) {
            f32x4 t0 = *(const f32x4*)(bb + ks * 32 + 0);
            f32x4 t1 = *(const f32x4*)(bb + ks * 32 + 4);
            bf16x8 bFk = pack2(t0, t1);
            acc = __builtin_amdgcn_mfma_f32_16x16x32_bf16(a2[ks], bFk, acc, 0, 0, 0);
        }
        float wb = Wb[ocol];
        #pragma unroll
        for (int r = 0; r < 4; ++r) {
            float v = acc[r] + wb;
            v = (v > 0.f) ? v : v * NEG_SLOPE;
            vout[ot][r] = v;
            sq[r] += v * v;
        }
    }
    #pragma unroll
    for (int r = 0; r < 4; ++r) {
        sq[r] += __shfl_xor(sq[r], 1);
        sq[r] += __shfl_xor(sq[r], 2);
        sq[r] += __shfl_xor(sq[r], 4);
        sq[r] += __shfl_xor(sq[r], 8);
    }
    if (lrow == 0) {
        #pragma unroll
        for (int r = 0; r < 4; ++r) s_part[wid][lk * 4 + r] = sq[r];
    }
    __syncthreads();
    if (tid < 16) {
        float s = s_part[0][tid] + s_part[1][tid] + s_part[2][tid] + s_part[3][tid];
        s_ninv[tid] = (s == 0.f) ? 1.f : 1.f / sqrtf(s);
    }
    __syncthreads();

    #pragma unroll
    for (int r = 0; r < 4; ++r) {
        int node = lk * 4 + r;
        int n = n0 + node;
        if (n < N) {
            float inv = s_ninv[node];
            #pragma unroll
            for (int ot = 0; ot < 4; ++ot)
                out[(long)n * O_DIM + wid * 64 + ot * 16 + lrow] = vout[ot][r] * inv;
        }
    }
}

extern "C" void kernel_launch(void* const* d_in, const int* in_sizes, int n_in,
                              void* d_out, int out_size, void* d_ws, size_t ws_size,
                              hipStream_t stream)
{
    const float* h        = (const float*)d_in[0];
    const int*   nodeset  = (const int*)  d_in[1];
    const int*   nb_nodes = (const int*)  d_in[2];
    const float* nb_w     = (const float*)d_in[3];
    const float* Qw       = (const float*)d_in[4];
    const float* Qb       = (const float*)d_in[5];
    const float* Ww       = (const float*)d_in[6];
    const float* Wb       = (const float*)d_in[7];
    float*       out      = (float*)d_out;

    int N = in_sizes[1];

    constexpr size_t QBYTES = (size_t)H_DIM * D_DIM * sizeof(ushort);   // 128 KB
    constexpr size_t WBYTES = (size_t)O_DIM * K2C * sizeof(ushort);     // 256 KB

    if (d_ws && ws_size >= QBYTES + WBYTES) {
        ushort* Qbf = (ushort*)d_ws;
        ushort* Wt  = (ushort*)((char*)d_ws + QBYTES);
        cvt_weights<<<(O_DIM * K2C + 255) / 256, 256, 0, stream>>>(Qw, Ww, Qbf, Wt);
        pinsage_fused<<<(N + NPB1 - 1) / NPB1, BLK1, 0, stream>>>(
            h, nodeset, nb_nodes, nb_w, Qbf, Qb, Wt, Wb, out, N);
    } else {
        pinsage_mono<<<(N + 15) / 16, 256, 0, stream>>>(
            h, nodeset, nb_nodes, nb_w, Qw, Qb, Ww, Wb, out, N);
    }
}